// Round 4
// baseline (244.097 us; speedup 1.0000x reference)
//
#include <hip/hip_runtime.h>
#include <stdint.h>

// SNN: B=1024, D_IN=1024, D_H=2048, D_OUT=256, T=50, beta=0.9, thr=1.0
// cur1 time-invariant -> spk1 precomputable; layer2 = one GEMM over M = T*B = 51200.
// gemm1: split-bf16 x3. gemm2: i8 double-pass (W2 = hi*256+lo, spk exact in i8),
// 32x32x32 i8 MFMA. R4: wave tile 64x64 (768 B LDS per MFMA, was 1280), block
// 128x128, grid (2,400) n-fastest for A L2/L3 reuse.

#define BATCH 1024
#define DIN   1024
#define DH    2048
#define DOUT  256
#define TSTEPS 50

typedef __bf16 bf16x8 __attribute__((ext_vector_type(8)));
typedef float  f32x4  __attribute__((ext_vector_type(4)));
typedef int    i32x4  __attribute__((ext_vector_type(4)));
typedef int    i32x16 __attribute__((ext_vector_type(16)));

__device__ __forceinline__ void gl2lds16(const void* g, void* l) {
  __builtin_amdgcn_global_load_lds(
      (const __attribute__((address_space(1))) uint32_t*)(uintptr_t)g,
      (__attribute__((address_space(3))) uint32_t*)(uint32_t)(uintptr_t)l,
      16, 0, 0);
}

__device__ __forceinline__ uint16_t f32_bf16_rne(float f) {
  uint32_t u = __float_as_uint(f);
  uint32_t r = u + 0x7FFFu + ((u >> 16) & 1u);
  return (uint16_t)(r >> 16);
}

// -------- split fp32 -> (hi, lo) bf16 --------
__global__ void split_kernel(const float* __restrict__ in, uint16_t* __restrict__ hi,
                             uint16_t* __restrict__ lo, int n) {
  int i = (blockIdx.x * 256 + threadIdx.x) * 4;
  if (i >= n) return;
  float4 v4 = *(const float4*)(in + i);
  float vv[4] = {v4.x, v4.y, v4.z, v4.w};
  uint32_t h[4], l[4];
#pragma unroll
  for (int k = 0; k < 4; ++k) {
    h[k] = f32_bf16_rne(vv[k]);
    float hf = __uint_as_float(h[k] << 16);
    l[k] = f32_bf16_rne(vv[k] - hf);
  }
  *(uint2*)(hi + i) = make_uint2(h[0] | (h[1] << 16), h[2] | (h[3] << 16));
  *(uint2*)(lo + i) = make_uint2(l[0] | (l[1] << 16), l[2] | (l[3] << 16));
}

// -------- W2 absmax (order-independent max -> deterministic) --------
__global__ void maxabs_kernel(const float* __restrict__ in, unsigned* __restrict__ mx, int n) {
  int i = (blockIdx.x * 256 + threadIdx.x) * 4;
  float4 v = *(const float4*)(in + i);
  float m = fmaxf(fmaxf(fabsf(v.x), fabsf(v.y)), fmaxf(fabsf(v.z), fabsf(v.w)));
#pragma unroll
  for (int o = 32; o; o >>= 1) m = fmaxf(m, __shfl_down(m, o, 64));
  if ((threadIdx.x & 63) == 0) atomicMax(mx, __float_as_uint(m));
}

// -------- W2 quantize: q = rint(w*S), S = 32512/max; q = hi*256 + lo --------
__global__ void quant_kernel(const float* __restrict__ in, const unsigned* __restrict__ mx,
                             int8_t* __restrict__ hi, int8_t* __restrict__ lo, int n) {
  int i = (blockIdx.x * 256 + threadIdx.x) * 4;
  if (i >= n) return;
  float S = 32512.0f / __uint_as_float(*mx);
  float4 v = *(const float4*)(in + i);
  float vv[4] = {v.x, v.y, v.z, v.w};
  int8_t h4[4], l4[4];
#pragma unroll
  for (int k = 0; k < 4; ++k) {
    int q = (int)rintf(vv[k] * S);
    int h = (q + 128) >> 8;
    h4[k] = (int8_t)h;
    l4[k] = (int8_t)(q - (h << 8));
  }
  *(uint32_t*)(hi + i) = (uint8_t)h4[0] | ((uint8_t)h4[1] << 8) | ((uint8_t)h4[2] << 16) | ((uint32_t)(uint8_t)h4[3] << 24);
  *(uint32_t*)(lo + i) = (uint8_t)l4[0] | ((uint8_t)l4[1] << 8) | ((uint8_t)l4[2] << 16) | ((uint32_t)(uint8_t)l4[3] << 24);
}

// -------- GEMM1: cur1[1024,2048] = x @ W1^T + b1, bf16x3, 64x64 tile --------
__global__ __launch_bounds__(256, 4) void gemm1_kernel(
    const uint16_t* __restrict__ Ah, const uint16_t* __restrict__ Al,
    const uint16_t* __restrict__ Bh, const uint16_t* __restrict__ Bl,
    const float* __restrict__ bias, float* __restrict__ C) {
  const int K = DIN, N = DH;
  __shared__ uint16_t sAh[64 * 32], sAl[64 * 32], sBh[64 * 32], sBl[64 * 32];
  int tid = threadIdx.x;
  int lane = tid & 63, wave = tid >> 6;
  int wm = (wave >> 1) * 32, wn = (wave & 1) * 32;
  int m0 = blockIdx.x * 64, n0 = blockIdx.y * 64;
  int rf = lane & 15;
  int cc = lane >> 4;

  f32x4 acc[2][2] = {};

  int sr = tid >> 2;
  int sc = (((tid & 3) - (sr >> 1)) & 3) * 8;

  for (int k0 = 0; k0 < K; k0 += 32) {
    gl2lds16(Ah + (size_t)(m0 + sr) * K + (k0 + sc), &sAh[tid * 8]);
    gl2lds16(Al + (size_t)(m0 + sr) * K + (k0 + sc), &sAl[tid * 8]);
    gl2lds16(Bh + (size_t)(n0 + sr) * K + (k0 + sc), &sBh[tid * 8]);
    gl2lds16(Bl + (size_t)(n0 + sr) * K + (k0 + sc), &sBl[tid * 8]);
    __syncthreads();

    bf16x8 ah[2], al[2], bh[2], bl[2];
#pragma unroll
    for (int i = 0; i < 2; ++i) {
      int R = wm + i * 16 + rf;
      int sl = ((cc + (R >> 1)) & 3) * 8;
      ah[i] = *(const bf16x8*)&sAh[R * 32 + sl];
      al[i] = *(const bf16x8*)&sAl[R * 32 + sl];
      int Rb = wn + i * 16 + rf;
      int slb = ((cc + (Rb >> 1)) & 3) * 8;
      bh[i] = *(const bf16x8*)&sBh[Rb * 32 + slb];
      bl[i] = *(const bf16x8*)&sBl[Rb * 32 + slb];
    }
#pragma unroll
    for (int i = 0; i < 2; ++i)
#pragma unroll
      for (int j = 0; j < 2; ++j) {
        acc[i][j] = __builtin_amdgcn_mfma_f32_16x16x32_bf16(ah[i], bh[j], acc[i][j], 0, 0, 0);
        acc[i][j] = __builtin_amdgcn_mfma_f32_16x16x32_bf16(ah[i], bl[j], acc[i][j], 0, 0, 0);
        acc[i][j] = __builtin_amdgcn_mfma_f32_16x16x32_bf16(al[i], bh[j], acc[i][j], 0, 0, 0);
      }
    __syncthreads();
  }

  int cq = (lane >> 4) * 4;
#pragma unroll
  for (int j = 0; j < 2; ++j) {
    int col = n0 + wn + j * 16 + rf;
    float bv = bias[col];
#pragma unroll
    for (int i = 0; i < 2; ++i) {
      size_t row = m0 + wm + i * 16 + cq;
      float* cp = C + row * N + col;
#pragma unroll
      for (int r = 0; r < 4; ++r) cp[(size_t)r * N] = acc[i][j][r] + bv;
    }
  }
}

// -------- GEMM2: cur2[M,256] = spk_i8[M,2048] @ W2q^T, 32x32x32 i8 --------
// Block 128m x 128n, wave 64x64 (2x2 of 32x32). 12 LDS reads feed 16 MFMAs.
__global__ __launch_bounds__(256, 2) void gemm2_kernel(
    const int8_t* __restrict__ A, const int8_t* __restrict__ Bh,
    const int8_t* __restrict__ Bl, const float* __restrict__ bias,
    const unsigned* __restrict__ mx, float* __restrict__ C) {
  const int K = DH, N = DOUT;
  __shared__ int8_t sA[128 * 64], sBh[128 * 64], sBl[128 * 64];
  int tid = threadIdx.x;
  int lane = tid & 63, wave = tid >> 6;
  int m0 = blockIdx.y * 128, n0 = blockIdx.x * 128;   // x = n-col (2): adjacent blocks share A-strip
  int wm = (wave >> 1) * 64, wn = (wave & 1) * 64;
  int rm = lane & 31;
  int half = lane >> 5;

  i32x16 acch[2][2] = {};
  i32x16 accl[2][2] = {};

  for (int k0 = 0; k0 < K; k0 += 64) {
#pragma unroll
    for (int ph = 0; ph < 2; ++ph) {     // 128 rows x 64 B = 512 units per array
      int u = tid + ph * 256;
      int r = u >> 2;
      int c = (((u & 3) - (r >> 1)) & 3) * 16;   // swizzled global chunk
      gl2lds16(A  + (size_t)(m0 + r) * K + (k0 + c), &sA[u * 16]);
      gl2lds16(Bh + (size_t)(n0 + r) * K + (k0 + c), &sBh[u * 16]);
      gl2lds16(Bl + (size_t)(n0 + r) * K + (k0 + c), &sBl[u * 16]);
    }
    __syncthreads();

    // frag k = ks*32 + half*16 + j; LDS slot = (ks*2+half + (row>>1)) & 3
    i32x4 a[2][2], bhf[2][2], blf[2][2];
#pragma unroll
    for (int ks = 0; ks < 2; ++ks) {
#pragma unroll
      for (int mi = 0; mi < 2; ++mi) {
        int Ra = wm + mi * 32 + rm;
        int sla = ((ks * 2 + half + (Ra >> 1)) & 3) * 16;
        a[mi][ks] = *(const i32x4*)&sA[Ra * 64 + sla];
      }
#pragma unroll
      for (int ni = 0; ni < 2; ++ni) {
        int Rb = wn + ni * 32 + rm;
        int slb = ((ks * 2 + half + (Rb >> 1)) & 3) * 16;
        bhf[ni][ks] = *(const i32x4*)&sBh[Rb * 64 + slb];
        blf[ni][ks] = *(const i32x4*)&sBl[Rb * 64 + slb];
      }
    }
#pragma unroll
    for (int ks = 0; ks < 2; ++ks)
#pragma unroll
      for (int mi = 0; mi < 2; ++mi)
#pragma unroll
        for (int ni = 0; ni < 2; ++ni) {
          acch[mi][ni] = __builtin_amdgcn_mfma_i32_32x32x32_i8(a[mi][ks], bhf[ni][ks], acch[mi][ni], 0, 0, 0);
          accl[mi][ni] = __builtin_amdgcn_mfma_i32_32x32x32_i8(a[mi][ks], blf[ni][ks], accl[mi][ni], 0, 0, 0);
        }
    __syncthreads();
  }

  // C/D 32x32: col = lane&31, row = (r&3) + 8*(r>>2) + 4*(lane>>5)
  float invS = __uint_as_float(*mx) * (1.0f / 32512.0f);
#pragma unroll
  for (int mi = 0; mi < 2; ++mi)
#pragma unroll
    for (int ni = 0; ni < 2; ++ni) {
      int col = n0 + wn + ni * 32 + rm;
      float bv = bias[col];
#pragma unroll
      for (int r = 0; r < 16; ++r) {
        int row = m0 + wm + mi * 32 + (r & 3) + 8 * (r >> 2) + 4 * half;
        int q = acch[mi][ni][r] * 256 + accl[mi][ni][r];   // exact i32
        C[(size_t)row * N + col] = (float)q * invS + bv;
      }
    }
}

// -------- LIF layer 1: recurrence, emit i8 spikes + h_sum --------
__global__ void lif1_kernel(const float* __restrict__ cur1, float* __restrict__ mem1,
                            int8_t* __restrict__ spk, float* __restrict__ hsum,
                            int tc, int init, int save_mem) {
#pragma clang fp contract(off)
  int idx = blockIdx.x * 256 + threadIdx.x;
  int e0 = idx * 8;
  float4 c0 = *(const float4*)(cur1 + e0);
  float4 c1 = *(const float4*)(cur1 + e0 + 4);
  float m[8] = {0, 0, 0, 0, 0, 0, 0, 0};
  if (!init) {
    float4 ma = *(const float4*)(mem1 + e0);
    float4 mb = *(const float4*)(mem1 + e0 + 4);
    m[0] = ma.x; m[1] = ma.y; m[2] = ma.z; m[3] = ma.w;
    m[4] = mb.x; m[5] = mb.y; m[6] = mb.z; m[7] = mb.w;
  }
  float c[8] = {c0.x, c0.y, c0.z, c0.w, c1.x, c1.y, c1.z, c1.w};
  float hs[8] = {0, 0, 0, 0, 0, 0, 0, 0};
  for (int t = 0; t < tc; ++t) {
    uint32_t b0 = 0, b1 = 0;
#pragma unroll
    for (int v = 0; v < 8; ++v) {
      float r = (m[v] > 1.0f) ? 1.0f : 0.0f;   // reset from PREVIOUS mem
      m[v] = 0.9f * m[v] + c[v] - r;           // contract(off): mul,add,sub like np
      bool s = (m[v] - 1.0f) > 0.0f;
      hs[v] += s ? 1.0f : 0.0f;
      uint32_t bit = s ? 1u : 0u;
      if (v < 4) b0 |= bit << (8 * v); else b1 |= bit << (8 * (v - 4));
    }
    *(uint2*)(spk + (size_t)t * (BATCH * DH) + e0) = make_uint2(b0, b1);
  }
  if (save_mem) {
    *(float4*)(mem1 + e0)     = make_float4(m[0], m[1], m[2], m[3]);
    *(float4*)(mem1 + e0 + 4) = make_float4(m[4], m[5], m[6], m[7]);
  }
  float4 h0, h1;
  if (init) {
    h0 = make_float4(hs[0], hs[1], hs[2], hs[3]);
    h1 = make_float4(hs[4], hs[5], hs[6], hs[7]);
  } else {
    h0 = *(float4*)(hsum + e0);
    h1 = *(float4*)(hsum + e0 + 4);
    h0.x += hs[0]; h0.y += hs[1]; h0.z += hs[2]; h0.w += hs[3];
    h1.x += hs[4]; h1.y += hs[5]; h1.z += hs[6]; h1.w += hs[7];
  }
  *(float4*)(hsum + e0)     = h0;
  *(float4*)(hsum + e0 + 4) = h1;
}

// -------- LIF layer 2 --------
__global__ void lif2_kernel(const float* __restrict__ cur2, float* __restrict__ mem2,
                            float* __restrict__ osum, int tc, int init, int save_mem) {
#pragma clang fp contract(off)
  int idx = blockIdx.x * 256 + threadIdx.x;
  float m = init ? 0.0f : mem2[idx];
  float os = 0.0f;
  for (int t = 0; t < tc; ++t) {
    float c = cur2[(size_t)t * (BATCH * DOUT) + idx];
    float r = (m > 1.0f) ? 1.0f : 0.0f;
    m = 0.9f * m + c - r;
    os += ((m - 1.0f) > 0.0f) ? 1.0f : 0.0f;
  }
  if (save_mem) mem2[idx] = m;
  osum[idx] = init ? os : (osum[idx] + os);
}

extern "C" void kernel_launch(void* const* d_in, const int* in_sizes, int n_in,
                              void* d_out, int out_size, void* d_ws, size_t ws_size,
                              hipStream_t stream) {
  const float* x  = (const float*)d_in[0];
  const float* W1 = (const float*)d_in[1];
  const float* b1 = (const float*)d_in[2];
  const float* W2 = (const float*)d_in[3];
  const float* b2 = (const float*)d_in[4];
  float* out = (float*)d_out;           // h_sum [1024*2048] then out_sum [1024*256]
  char* ws = (char*)d_ws;

  const size_t fixed = 32 * 1024 * 1024;
  int tc = 10;
  if (ws_size >= fixed + 50ull * (2097152 + 1048576)) tc = 50;
  else if (ws_size >= fixed + 25ull * (2097152 + 1048576)) tc = 25;
  int nchunk = TSTEPS / tc;

  size_t off = 0;
  auto alloc = [&](size_t b) { size_t p = off; off = (off + b + 255) & ~(size_t)255; return p; };
  uint16_t* xh   = (uint16_t*)(ws + alloc(2097152));
  uint16_t* xl   = (uint16_t*)(ws + alloc(2097152));
  uint16_t* w1h  = (uint16_t*)(ws + alloc(4194304));
  uint16_t* w1l  = (uint16_t*)(ws + alloc(4194304));
  int8_t*   w2h  = (int8_t*)(ws + alloc(524288));
  int8_t*   w2l  = (int8_t*)(ws + alloc(524288));
  unsigned* w2mx = (unsigned*)(ws + alloc(256));
  float*    cur1 = (float*)(ws + alloc(8388608));
  float*    mem1 = (float*)(ws + alloc(8388608));
  float*    mem2 = (float*)(ws + alloc(1048576));
  int8_t*   spkc = (int8_t*)(ws + alloc((size_t)tc * BATCH * DH));
  float*    cur2c = (float*)(ws + alloc((size_t)tc * BATCH * DOUT * 4));

  hipMemsetAsync(w2mx, 0, 4, stream);
  if (nchunk > 1) {
    hipMemsetAsync(mem1, 0, 8388608, stream);
    hipMemsetAsync(mem2, 0, 1048576, stream);
  }

  split_kernel<<<1024, 256, 0, stream>>>(x,  xh,  xl,  BATCH * DIN);
  split_kernel<<<2048, 256, 0, stream>>>(W1, w1h, w1l, DH * DIN);
  maxabs_kernel<<<512, 256, 0, stream>>>(W2, w2mx, DOUT * DH);
  quant_kernel<<<512, 256, 0, stream>>>(W2, w2mx, w2h, w2l, DOUT * DH);

  gemm1_kernel<<<dim3(BATCH / 64, DH / 64), 256, 0, stream>>>(xh, xl, w1h, w1l, b1, cur1);

  int save = (nchunk > 1) ? 1 : 0;
  for (int c = 0; c < nchunk; ++c) {
    int init = (c == 0) ? 1 : 0;
    lif1_kernel<<<(BATCH * DH) / (256 * 8), 256, 0, stream>>>(cur1, mem1, spkc, out, tc, init, save);
    gemm2_kernel<<<dim3(DOUT / 128, (tc * BATCH) / 128), 256, 0, stream>>>(
        spkc, w2h, w2l, b2, w2mx, cur2c);
    lif2_kernel<<<(BATCH * DOUT) / 256, 256, 0, stream>>>(cur2c, mem2, out + BATCH * DH, tc, init, save);
  }
}